// Round 10
// baseline (1876.022 us; speedup 1.0000x reference)
//
#include <hip/hip_runtime.h>

typedef unsigned short u16;
typedef unsigned int   u32;
typedef __attribute__((ext_vector_type(8))) short bf16x8;  // 8 bf16 (4 VGPRs)
typedef __attribute__((ext_vector_type(4))) float f32x4;   // 4 fp32

// ---------- bf16 helpers (manual, RNE) ----------
__device__ __forceinline__ float bf2f(u16 u) { return __uint_as_float(((u32)u) << 16); }
__device__ __forceinline__ float bflo(u32 u) { return __uint_as_float(u << 16); }
__device__ __forceinline__ float bfhi(u32 u) { return __uint_as_float(u & 0xffff0000u); }
__device__ __forceinline__ u16 f2bf(float f) {
    u32 x = __float_as_uint(f);
    x += 0x7fffu + ((x >> 16) & 1u);   // round-to-nearest-even
    return (u16)(x >> 16);
}
// ---------- fp16 helpers (hardware cvt, RNE) ----------
__device__ __forceinline__ u16 f2h(float f) {
    _Float16 h = (_Float16)f;
    return __builtin_bit_cast(u16, h);
}
__device__ __forceinline__ float h2f(u16 u) {
    return (float)__builtin_bit_cast(_Float16, u);
}

// ---------- repack conv2 weights: w2r[kk][ccc][co][cil] bf16 ----------
__global__ __launch_bounds__(256) void repack_w2_kernel(const float* __restrict__ w2,
                                                        u16* __restrict__ w2r) {
    int idx = blockIdx.x * 256 + threadIdx.x;      // 81*8*256*32 = 5,308,416
    int cil = idx & 31;
    int co  = (idx >> 5) & 255;
    int ccc = (idx >> 13) & 7;
    int kk  = idx >> 16;
    int ci  = ccc * 32 + cil;
    w2r[idx] = f2bf(w2[(size_t)co * 20736 + (size_t)ci * 81 + kk]);
}

// ---------- repack W: Wt2[i][je][d] f32 from W[j][i][d][e] ----------
__global__ __launch_bounds__(256) void repack_W_kernel(const float* __restrict__ W,
                                                       float* __restrict__ Wt2) {
    int idx = blockIdx.x * 256 + threadIdx.x;      // total 1152*160*8 = 1,474,560
    int d  = idx & 7;
    int je = (idx >> 3) % 160;
    int i  = idx / 1280;
    int j = je >> 4, e = je & 15;
    Wt2[idx] = W[(((size_t)j * 1152 + i) * 8 + d) * 16 + e];
}

// ---------- conv1 (9x9 s1) + bias + bf16 store [b][p][co] + BN1 stats ----------
__global__ __launch_bounds__(256) void conv1_kernel(const float* __restrict__ x,
                                                    const float* __restrict__ w1,
                                                    const float* __restrict__ b1,
                                                    u16* __restrict__ y,
                                                    float* __restrict__ sum1,
                                                    float* __restrict__ sumsq1) {
    __shared__ float xs[784];
    const int b = blockIdx.x;
    const int t = threadIdx.x;          // co
    const float* xb = x + (size_t)b * 784;
    for (int idx = t; idx < 784; idx += 256) xs[idx] = xb[idx];
    float w[81];
#pragma unroll
    for (int q = 0; q < 81; ++q) w[q] = w1[(size_t)t * 81 + q];
    const float bias = b1[t];
    __syncthreads();

    float sl = 0.f, ssl = 0.f;
    u16* yb = y + (size_t)b * 400 * 256 + t;     // channels-last, stride 256
    for (int oh = 0; oh < 20; ++oh) {
        float acc[20];
#pragma unroll
        for (int ow = 0; ow < 20; ++ow) acc[ow] = bias;
#pragma unroll
        for (int kh = 0; kh < 9; ++kh) {
            const float4* rp = (const float4*)(&xs[(oh + kh) * 28]);
            float r[28];
#pragma unroll
            for (int k4 = 0; k4 < 7; ++k4) {
                float4 f = rp[k4];
                r[k4 * 4 + 0] = f.x; r[k4 * 4 + 1] = f.y;
                r[k4 * 4 + 2] = f.z; r[k4 * 4 + 3] = f.w;
            }
#pragma unroll
            for (int kw = 0; kw < 9; ++kw) {
                const float wv = w[kh * 9 + kw];
#pragma unroll
                for (int ow = 0; ow < 20; ++ow)
                    acc[ow] = fmaf(wv, r[ow + kw], acc[ow]);
            }
        }
#pragma unroll
        for (int ow = 0; ow < 20; ++ow) {
            u16 q = f2bf(acc[ow]);
            float rv = bf2f(q);
            sl += rv; ssl += rv * rv;
            yb[(size_t)(oh * 20 + ow) * 256] = q;
        }
    }
    atomicAdd(&sum1[t], sl);
    atomicAdd(&sumsq1[t], ssl);
}

// ---------- BN finalize ----------
__global__ void finalize_bn_kernel(const float* __restrict__ sum,
                                   const float* __restrict__ sumsq,
                                   const float* __restrict__ gam,
                                   const float* __restrict__ bet,
                                   float* __restrict__ scale,
                                   float* __restrict__ shift, float inv_n) {
    int c = threadIdx.x;
    float m = sum[c] * inv_n;
    float var = sumsq[c] * inv_n - m * m;
    float sc = gam[c] * rsqrtf(var + 1e-5f);
    scale[c] = sc;
    shift[c] = bet[c] - m * sc;
}

// ---------- BN1 + ReLU in-place on y ----------
__global__ __launch_bounds__(256) void bnpack_kernel(u32* __restrict__ y32,
                                                     const float* __restrict__ scale1,
                                                     const float* __restrict__ shift1) {
    const int b = blockIdx.x;
    const int t = threadIdx.x;
    const int c2 = (t & 127) * 2;
    const float s0 = scale1[c2],     s1 = scale1[c2 + 1];
    const float h0 = shift1[c2],     h1 = shift1[c2 + 1];
    u32* base = y32 + (size_t)b * 51200;
    for (int q = 0; q < 200; ++q) {
        const int idx = t + q * 256;
        u32 v = base[idx];
        float a = fmaxf(0.f, fmaf(s0, bflo(v), h0));
        float c = fmaxf(0.f, fmaf(s1, bfhi(v), h1));
        base[idx] = (u32)f2bf(a) | ((u32)f2bf(c) << 16);
    }
}

// ---------- conv2: implicit-im2col bf16 MFMA, software-pipelined staging ----------
// 512 blocks: g = blk>>1 (image pair), cb = (blk&1)*128 (co slice).
// 162 stages = 81 kk x 2 ci-halves; double-buffered LDS patch[2][84x136]
// (72 data rows = 2 img x 36 pos, rows 72..83 zero pad for wave-1's 48-row
// B-window overhang; garbage cols discarded via pos<36 guard).
// Stage s: barrier -> issue s+1 global loads to regs -> compute buf[s&1] ->
// write regs to buf[(s+1)&1]. Load latency overlaps 48 MFMAs + weight loads.
// K order (kk, ci ascending) identical to r9 => bit-identical z.
__global__ __launch_bounds__(256) void conv2_mfma_kernel(const u16* __restrict__ y,
                                                         const u16* __restrict__ w2r,
                                                         const float* __restrict__ b2,
                                                         float* __restrict__ z_raw,
                                                         float* __restrict__ sum2,
                                                         float* __restrict__ sumsq2) {
    __shared__ __align__(16) u16 patch[2][84 * 136];   // 2 x 22,848 B = 45.7 KB
    const int g  = blockIdx.x >> 1;
    const int cb = (blockIdx.x & 1) * 128;
    const int b0 = g * 2;
    const int t = threadIdx.x;
    const int wave = t >> 6, lane = t & 63;
    const int n16 = lane & 15, quad = lane >> 4;
    const int img = wave & 1, c64 = wave >> 1;         // wave: image, 64-co half of slice

    // zero pad rows 72..83 of both buffers (published by first loop barrier)
    for (int v = t; v < 2 * 12 * 68; v += 256) {
        const int buf = v / (12 * 68), rest = v - buf * (12 * 68);
        ((u32*)(patch[buf] + 72 * 136))[rest] = 0;
    }

    f32x4 zero = {0.f, 0.f, 0.f, 0.f};
    f32x4 acc[4][3];
#pragma unroll
    for (int ct = 0; ct < 4; ++ct)
#pragma unroll
        for (int pt = 0; pt < 3; ++pt) acc[ct][pt] = zero;

    uint4 rg[5];
    const int vr  = t >> 4;              // staging row slice base (v = t + q*256)
    const int c16 = t & 15;

    // prologue: stage 0 into buf 0 (no barrier needed yet; same-thread order)
    {
        const int kh = 0, kw = 0, cp = 0;
#pragma unroll
        for (int q = 0; q < 5; ++q) {
            const int v = t + q * 256;
            if (v < 1152) {
                const int r = v >> 4;
                const int il = (r >= 36) ? 1 : 0;
                const int pos = r - 36 * il;
                const int oh = (pos * 43) >> 8, ow = pos - oh * 6;
                const int ip = (2 * oh + kh) * 20 + (2 * ow + kw);
                rg[q] = *((const uint4*)(y + ((size_t)(b0 + il) * 400 + ip) * 256
                                         + cp * 128 + (v & 15) * 8));
            }
        }
#pragma unroll
        for (int q = 0; q < 5; ++q) {
            const int v = t + q * 256;
            if (v < 1152) *((uint4*)(patch[0] + (v >> 4) * 136 + (v & 15) * 8)) = rg[q];
        }
    }

    for (int s = 0; s < 162; ++s) {
        const int p = s & 1;
        __syncthreads();                 // buf[p] writes (+pad zeros) visible
        if (s < 161) {                   // issue next stage's loads
            const int sn = s + 1;
            const int kkn = sn >> 1, cpn = sn & 1;
            const int khn = kkn / 9, kwn = kkn - khn * 9;
#pragma unroll
            for (int q = 0; q < 5; ++q) {
                const int v = t + q * 256;
                if (v < 1152) {
                    const int r = v >> 4;
                    const int il = (r >= 36) ? 1 : 0;
                    const int pos = r - 36 * il;
                    const int oh = (pos * 43) >> 8, ow = pos - oh * 6;
                    const int ip = (2 * oh + khn) * 20 + (2 * ow + kwn);
                    rg[q] = *((const uint4*)(y + ((size_t)(b0 + il) * 400 + ip) * 256
                                             + cpn * 128 + (v & 15) * 8));
                }
            }
        }
        // compute on buf[p]: (kk, cp) = (s>>1, s&1)
        const int kk = s >> 1, cp = s & 1;
        const u16* wk = w2r + (size_t)kk * 65536 + (size_t)cp * 32768;
#pragma unroll
        for (int ccc = 0; ccc < 4; ++ccc) {
            bf16x8 bfr[3];
            const u16* pb = patch[p] + (img * 36 + n16) * 136 + ccc * 32 + quad * 8;
#pragma unroll
            for (int pt = 0; pt < 3; ++pt)
                bfr[pt] = *((const bf16x8*)(pb + pt * 2176));   // 16 rows * 136
            const u16* wa = wk + (size_t)ccc * 8192 + (cb + c64 * 64 + n16) * 32 + quad * 8;
#pragma unroll
            for (int ct = 0; ct < 4; ++ct) {
                bf16x8 afr = *((const bf16x8*)(wa + ct * 512));  // 16 co * 32
#pragma unroll
                for (int pt = 0; pt < 3; ++pt)
                    acc[ct][pt] = __builtin_amdgcn_mfma_f32_16x16x32_bf16(
                        afr, bfr[pt], acc[ct][pt], 0, 0, 0);
            }
        }
        if (s < 161) {                   // write next stage into the other buffer
#pragma unroll
            for (int q = 0; q < 5; ++q) {
                const int v = t + q * 256;
                if (v < 1152) *((uint4*)(patch[p ^ 1] + (v >> 4) * 136 + (v & 15) * 8)) = rg[q];
            }
        }
    }

    // epilogue: bias, store z[b0+img][co][36], BN2 stats (identical to r9)
#pragma unroll
    for (int ct = 0; ct < 4; ++ct) {
#pragma unroll
        for (int r = 0; r < 4; ++r) {
            const int co = cb + c64 * 64 + ct * 16 + quad * 4 + r;
            const float bias = b2[co];
            float s = 0.f, ss = 0.f;
#pragma unroll
            for (int pt = 0; pt < 3; ++pt) {
                const int pos = pt * 16 + n16;
                if (pos < 36) {
                    float v = acc[ct][pt][r] + bias;
                    z_raw[((size_t)(b0 + img) * 256 + co) * 36 + pos] = v;
                    s += v; ss += v * v;
                }
            }
#pragma unroll
            for (int m = 1; m < 16; m <<= 1) {
                s  += __shfl_xor(s,  m, 64);
                ss += __shfl_xor(ss, m, 64);
            }
            if (n16 == 0) { atomicAdd(&sum2[co], s); atomicAdd(&sumsq2[co], ss); }
        }
    }
}

// ---------- BN2 + ReLU + capsule transpose: ut fp16 [b][d][i] ----------
__global__ __launch_bounds__(256) void ubuild_kernel(const float* __restrict__ z_raw,
                                                     const float* __restrict__ scale2,
                                                     const float* __restrict__ shift2,
                                                     u16* __restrict__ ut16) {
    const int b = blockIdx.x;
    const int t = threadIdx.x;            // c
    const int d = t >> 5, m = t & 31;
    const float sc = scale2[t], sh = shift2[t];
    const float* zp = z_raw + ((size_t)b * 256 + t) * 36;
    u32* up = (u32*)(ut16 + ((size_t)b * 8 + d) * 1152 + m * 36);
#pragma unroll
    for (int q = 0; q < 18; ++q) {
        float v0 = fmaxf(0.f, fmaf(sc, zp[2 * q],     sh));
        float v1 = fmaxf(0.f, fmaf(sc, zp[2 * q + 1], sh));
        up[q] = (u32)f2h(v0) | ((u32)f2h(v1) << 16);
    }
}

// ---------- u_hat_f16[b][i][je] = sum_d ut[b][d][i]*Wt2[i][je][d]; + s0 partials ----------
__global__ __launch_bounds__(256) void uhat_kernel(const u16* __restrict__ ut16,
                                                   const float* __restrict__ Wt2,
                                                   u16* __restrict__ u_hat,
                                                   float* __restrict__ s0g) {
    __shared__ float utl[8 * 8 * 144];    // [bb][d][ii], 36 KB
    const int bg = blockIdx.x >> 3;       // 64 image-groups of 8
    const int ic = blockIdx.x & 7;        // 8 i-chunks of 144
    const int b0 = bg * 8, i0 = ic * 144;
    for (int v = threadIdx.x; v < 8 * 8 * 144; v += 256) {
        int ii = v % 144; int d = (v / 144) & 7; int bb = v / 1152;
        utl[v] = h2f(ut16[(size_t)(b0 + bb) * 9216 + d * 1152 + i0 + ii]);
    }
    __syncthreads();
    for (int q = 0; q < 90; ++q) {
        int o = q * 256 + threadIdx.x;    // 144*160 = 23040 = 90*256
        int ii = o / 160, je = o - ii * 160;
        const float* wp = Wt2 + ((size_t)(i0 + ii) * 160 + je) * 8;
        float w[8];
#pragma unroll
        for (int d = 0; d < 8; ++d) w[d] = wp[d];
#pragma unroll
        for (int bb = 0; bb < 8; ++bb) {
            float acc = 0.f;
#pragma unroll
            for (int d = 0; d < 8; ++d) acc = fmaf(w[d], utl[bb * 1152 + d * 144 + ii], acc);
            u_hat[(size_t)(b0 + bb) * 184320 + (size_t)(i0 + ii) * 160 + je] = f2h(acc);
        }
    }
    __syncthreads();   // drains stores (compiler emits vmcnt(0) before barrier)
    // s0 partials: 1280 (bb,je) pairs, 5 per thread; re-read own L2-hot tile
#pragma unroll
    for (int p = 0; p < 5; ++p) {
        const int pair = p * 256 + threadIdx.x;
        const int bb = pair / 160, je = pair - (pair / 160) * 160;
        const u16* up = u_hat + (size_t)(b0 + bb) * 184320 + (size_t)i0 * 160 + je;
        float s = 0.f;
        for (int ii = 0; ii < 144; ++ii) s += h2f(up[(size_t)ii * 160]);
        atomicAdd(&s0g[(size_t)(b0 + bb) * 160 + je], s);
    }
}

// ---------- fused routing, iterations 1..4 (iter-0 s precomputed), double-buffered ----------
__global__ __launch_bounds__(384) void routing_kernel(const u16* __restrict__ u_hat,
                                                      const float* __restrict__ s0g,
                                                      float* __restrict__ out) {
    __shared__ __align__(16) u16 uhs[2][96 * 168]; // 2 x 31.5 KB, row pad 168
    __shared__ float cl[10 * 96];
    __shared__ float part[320];
    __shared__ float sv[160];
    const int t = threadIdx.x;
    const int b = blockIdx.x;
    const u16* uh = u_hat + (size_t)b * 184320;
    const int hB = (t < 320) ? (t / 160) : 0;
    const int je = (t < 320) ? (t - hB * 160) : 0;
    const int jB = je >> 4;

    float bl[12][10];
#pragma unroll
    for (int c = 0; c < 12; ++c)
#pragma unroll
        for (int j = 0; j < 10; ++j) bl[c][j] = 0.f;

    // issue chunk-0 loads, then v0 = squash(0.1 * s0)
    uint4 rg[5];
    {
        const u16* src = uh;
#pragma unroll
        for (int q = 0; q < 5; ++q) {
            int v = t + q * 384, r = v / 20, c16 = v - r * 20;
            rg[q] = *((const uint4*)(src + r * 160 + c16 * 8));
        }
    }
    if (t < 160) sv[t] = 0.1f * s0g[(size_t)b * 160 + t];
    __syncthreads();
    if (t < 10) {
        float n2 = 0.f;
#pragma unroll
        for (int e2 = 0; e2 < 16; ++e2) { float xx = sv[t * 16 + e2]; n2 += xx * xx; }
        float n = sqrtf(n2);
        float f = n / (n2 + 1.f);
#pragma unroll
        for (int e2 = 0; e2 < 16; ++e2) sv[t * 16 + e2] *= f;
    }
    // write chunk 0 into buf 0
#pragma unroll
    for (int q = 0; q < 5; ++q) {
        int v = t + q * 384, r = v / 20, c16 = v - r * 20;
        *((uint4*)(&uhs[0][r * 168 + c16 * 8])) = rg[q];
    }

    for (int k = 1; k <= 4; ++k) {
        float sacc = 0.f;
        for (int c = 0; c < 12; ++c) {
            const int p = c & 1;
            const bool last = (k == 4) && (c == 11);
            __syncthreads();               // buf[p] writes + sv/cl updates visible
            if (!last) {                   // issue next-chunk loads (wraps to 0 across k)
                const int nc = (c == 11) ? 0 : c + 1;
                const u16* src = uh + (size_t)nc * 15360;
#pragma unroll
                for (int q = 0; q < 5; ++q) {
                    int v = t + q * 384, r = v / 20, c16 = v - r * 20;
                    rg[q] = *((const uint4*)(src + r * 160 + c16 * 8));
                }
            }
            if (t < 96) {                  // phase A
                const u16* row = uhs[p] + t * 168;
                float bj[10];
#pragma unroll
                for (int j = 0; j < 10; ++j) {
                    uint4 a = *((const uint4*)(row + j * 16));
                    uint4 bq = *((const uint4*)(row + j * 16 + 8));
                    const float* vv = &sv[j * 16];
                    float dj = h2f((u16)(a.x & 0xffff)) * vv[0]  + h2f((u16)(a.x >> 16)) * vv[1]
                             + h2f((u16)(a.y & 0xffff)) * vv[2]  + h2f((u16)(a.y >> 16)) * vv[3]
                             + h2f((u16)(a.z & 0xffff)) * vv[4]  + h2f((u16)(a.z >> 16)) * vv[5]
                             + h2f((u16)(a.w & 0xffff)) * vv[6]  + h2f((u16)(a.w >> 16)) * vv[7]
                             + h2f((u16)(bq.x & 0xffff)) * vv[8]  + h2f((u16)(bq.x >> 16)) * vv[9]
                             + h2f((u16)(bq.y & 0xffff)) * vv[10] + h2f((u16)(bq.y >> 16)) * vv[11]
                             + h2f((u16)(bq.z & 0xffff)) * vv[12] + h2f((u16)(bq.z >> 16)) * vv[13]
                             + h2f((u16)(bq.w & 0xffff)) * vv[14] + h2f((u16)(bq.w >> 16)) * vv[15];
                    bl[c][j] += dj;
                    bj[j] = bl[c][j];
                }
                float mx = bj[0];
#pragma unroll
                for (int j = 1; j < 10; ++j) mx = fmaxf(mx, bj[j]);
                float s = 0.f;
#pragma unroll
                for (int j = 0; j < 10; ++j) { bj[j] = __expf(bj[j] - mx); s += bj[j]; }
                float inv = 1.f / s;
#pragma unroll
                for (int j = 0; j < 10; ++j) cl[j * 96 + t] = bj[j] * inv;
            }
            __syncthreads();               // cl visible
            if (t < 320) {                 // phase B
                const int r0 = hB * 48;
#pragma unroll 4
                for (int il = 0; il < 48; ++il) {
                    const int r = r0 + il;
                    sacc = fmaf(cl[jB * 96 + r], h2f(uhs[p][r * 168 + je]), sacc);
                }
            }
            if (!last) {                   // write next chunk into the other buffer
#pragma unroll
                for (int q = 0; q < 5; ++q) {
                    int v = t + q * 384, r = v / 20, c16 = v - r * 20;
                    *((uint4*)(&uhs[p ^ 1][r * 168 + c16 * 8])) = rg[q];
                }
            }
        }
        __syncthreads();
        if (t < 320) part[t] = sacc;
        __syncthreads();
        if (t < 160) sv[t] = part[t] + part[t + 160];
        __syncthreads();
        if (t < 10) {
            float n2 = 0.f;
#pragma unroll
            for (int e2 = 0; e2 < 16; ++e2) { float xx = sv[t * 16 + e2]; n2 += xx * xx; }
            float n = sqrtf(n2);
            float f = n / (n2 + 1.f);
#pragma unroll
            for (int e2 = 0; e2 < 16; ++e2) sv[t * 16 + e2] *= f;
        }
    }
    __syncthreads();
    if (t < 160) out[(size_t)b * 160 + t] = sv[t];
}

extern "C" void kernel_launch(void* const* d_in, const int* in_sizes, int n_in,
                              void* d_out, int out_size, void* d_ws, size_t ws_size,
                              hipStream_t stream) {
    const float* x   = (const float*)d_in[0];
    const float* w1  = (const float*)d_in[1];
    const float* b1  = (const float*)d_in[2];
    const float* g1  = (const float*)d_in[3];
    const float* be1 = (const float*)d_in[4];
    const float* w2  = (const float*)d_in[5];
    const float* b2  = (const float*)d_in[6];
    const float* g2  = (const float*)d_in[7];
    const float* be2 = (const float*)d_in[8];
    const float* W   = (const float*)d_in[9];
    float* out = (float*)d_out;

    // ---- workspace layout (peak 213,524,480 B == proven-safe bound) ----
    const size_t OFF_UHAT = 8192;                       // 188,743,680 B (fp16, full batch)
    const size_t OFF_Y    = 8192;                       // 104,857,600 B (in u_hat region)
    const size_t OFF_W2R  = 104865792ull;               //  10,616,832 B (in u_hat region)
    const size_t OFF_Z    = 126099456ull;               //  18,874,368 B (in u_hat region)
    const size_t OFF_UT   = 188751872ull;               //   9,437,184 B (ut fp16)
    const size_t OFF_S0   = 198189056ull;               //     327,680 B (s0)
    const size_t OFF_WT   = 207626240ull;               //   5,898,240 B
    const size_t WS_NEED  = 213524480ull;
    if (ws_size < WS_NEED) return;

    char* ws = (char*)d_ws;
    float* sum1   = (float*)(ws + 0);
    float* sumsq1 = (float*)(ws + 1024);
    float* sum2   = (float*)(ws + 2048);
    float* sumsq2 = (float*)(ws + 3072);
    float* scale1 = (float*)(ws + 4096);
    float* shift1 = (float*)(ws + 5120);
    float* scale2 = (float*)(ws + 6144);
    float* shift2 = (float*)(ws + 7168);
    u16*   y     = (u16*)(ws + OFF_Y);
    u16*   w2r   = (u16*)(ws + OFF_W2R);
    float* z_raw = (float*)(ws + OFF_Z);
    u16*   ut16  = (u16*)(ws + OFF_UT);
    float* s0g   = (float*)(ws + OFF_S0);
    float* Wt2   = (float*)(ws + OFF_WT);
    u16*   u_hat = (u16*)(ws + OFF_UHAT);

    hipMemsetAsync(ws, 0, 4096, stream);               // BN sums
    hipMemsetAsync(ws + OFF_S0, 0, 327680, stream);    // s0 accumulators

    hipLaunchKernelGGL(repack_w2_kernel, dim3(20736), dim3(256), 0, stream, w2, w2r);
    hipLaunchKernelGGL(repack_W_kernel,  dim3(5760),  dim3(256), 0, stream, W, Wt2);
    hipLaunchKernelGGL(conv1_kernel,     dim3(512),   dim3(256), 0, stream,
                       x, w1, b1, y, sum1, sumsq1);
    hipLaunchKernelGGL(finalize_bn_kernel, dim3(1), dim3(256), 0, stream,
                       sum1, sumsq1, g1, be1, scale1, shift1, 1.f / 204800.f);
    hipLaunchKernelGGL(bnpack_kernel,    dim3(512),   dim3(256), 0, stream,
                       (u32*)y, scale1, shift1);
    hipLaunchKernelGGL(conv2_mfma_kernel, dim3(512),  dim3(256), 0, stream,
                       y, w2r, b2, z_raw, sum2, sumsq2);
    hipLaunchKernelGGL(finalize_bn_kernel, dim3(1), dim3(256), 0, stream,
                       sum2, sumsq2, g2, be2, scale2, shift2, 1.f / 18432.f);
    hipLaunchKernelGGL(ubuild_kernel,    dim3(512),   dim3(256), 0, stream,
                       z_raw, scale2, shift2, ut16);
    hipLaunchKernelGGL(uhat_kernel,      dim3(512),   dim3(256), 0, stream,
                       ut16, Wt2, u_hat, s0g);
    hipLaunchKernelGGL(routing_kernel,   dim3(512),   dim3(384), 0, stream,
                       u_hat, s0g, out);
}

// Round 11
// 1222.029 us; speedup vs baseline: 1.5352x; 1.5352x over previous
//
#include <hip/hip_runtime.h>

typedef unsigned short u16;
typedef unsigned int   u32;
typedef __attribute__((ext_vector_type(8))) short bf16x8;  // 8 bf16 (4 VGPRs)
typedef __attribute__((ext_vector_type(4))) float f32x4;   // 4 fp32

// ---------- bf16 helpers (manual, RNE) ----------
__device__ __forceinline__ float bf2f(u16 u) { return __uint_as_float(((u32)u) << 16); }
__device__ __forceinline__ float bflo(u32 u) { return __uint_as_float(u << 16); }
__device__ __forceinline__ float bfhi(u32 u) { return __uint_as_float(u & 0xffff0000u); }
__device__ __forceinline__ u16 f2bf(float f) {
    u32 x = __float_as_uint(f);
    x += 0x7fffu + ((x >> 16) & 1u);   // round-to-nearest-even
    return (u16)(x >> 16);
}
// ---------- fp16 helpers (hardware cvt, RNE) ----------
__device__ __forceinline__ u16 f2h(float f) {
    _Float16 h = (_Float16)f;
    return __builtin_bit_cast(u16, h);
}
__device__ __forceinline__ float h2f(u16 u) {
    return (float)__builtin_bit_cast(_Float16, u);
}

// ---------- repack conv2 weights: w2r[kk][ccc][co][cil] bf16 ----------
__global__ __launch_bounds__(256) void repack_w2_kernel(const float* __restrict__ w2,
                                                        u16* __restrict__ w2r) {
    int idx = blockIdx.x * 256 + threadIdx.x;      // 81*8*256*32 = 5,308,416
    int cil = idx & 31;
    int co  = (idx >> 5) & 255;
    int ccc = (idx >> 13) & 7;
    int kk  = idx >> 16;
    int ci  = ccc * 32 + cil;
    w2r[idx] = f2bf(w2[(size_t)co * 20736 + (size_t)ci * 81 + kk]);
}

// ---------- repack W: Wt2[i][je][d] f32 from W[j][i][d][e] ----------
__global__ __launch_bounds__(256) void repack_W_kernel(const float* __restrict__ W,
                                                       float* __restrict__ Wt2) {
    int idx = blockIdx.x * 256 + threadIdx.x;      // total 1152*160*8 = 1,474,560
    int d  = idx & 7;
    int je = (idx >> 3) % 160;
    int i  = idx / 1280;
    int j = je >> 4, e = je & 15;
    Wt2[idx] = W[(((size_t)j * 1152 + i) * 8 + d) * 16 + e];
}

// ---------- conv1 (9x9 s1) + bias + bf16 store [b][p][co] + BN1 stats ----------
__global__ __launch_bounds__(256) void conv1_kernel(const float* __restrict__ x,
                                                    const float* __restrict__ w1,
                                                    const float* __restrict__ b1,
                                                    u16* __restrict__ y,
                                                    float* __restrict__ sum1,
                                                    float* __restrict__ sumsq1) {
    __shared__ float xs[784];
    const int b = blockIdx.x;
    const int t = threadIdx.x;          // co
    const float* xb = x + (size_t)b * 784;
    for (int idx = t; idx < 784; idx += 256) xs[idx] = xb[idx];
    float w[81];
#pragma unroll
    for (int q = 0; q < 81; ++q) w[q] = w1[(size_t)t * 81 + q];
    const float bias = b1[t];
    __syncthreads();

    float sl = 0.f, ssl = 0.f;
    u16* yb = y + (size_t)b * 400 * 256 + t;     // channels-last, stride 256
    for (int oh = 0; oh < 20; ++oh) {
        float acc[20];
#pragma unroll
        for (int ow = 0; ow < 20; ++ow) acc[ow] = bias;
#pragma unroll
        for (int kh = 0; kh < 9; ++kh) {
            const float4* rp = (const float4*)(&xs[(oh + kh) * 28]);
            float r[28];
#pragma unroll
            for (int k4 = 0; k4 < 7; ++k4) {
                float4 f = rp[k4];
                r[k4 * 4 + 0] = f.x; r[k4 * 4 + 1] = f.y;
                r[k4 * 4 + 2] = f.z; r[k4 * 4 + 3] = f.w;
            }
#pragma unroll
            for (int kw = 0; kw < 9; ++kw) {
                const float wv = w[kh * 9 + kw];
#pragma unroll
                for (int ow = 0; ow < 20; ++ow)
                    acc[ow] = fmaf(wv, r[ow + kw], acc[ow]);
            }
        }
#pragma unroll
        for (int ow = 0; ow < 20; ++ow) {
            u16 q = f2bf(acc[ow]);
            float rv = bf2f(q);
            sl += rv; ssl += rv * rv;
            yb[(size_t)(oh * 20 + ow) * 256] = q;
        }
    }
    atomicAdd(&sum1[t], sl);
    atomicAdd(&sumsq1[t], ssl);
}

// ---------- BN finalize ----------
__global__ void finalize_bn_kernel(const float* __restrict__ sum,
                                   const float* __restrict__ sumsq,
                                   const float* __restrict__ gam,
                                   const float* __restrict__ bet,
                                   float* __restrict__ scale,
                                   float* __restrict__ shift, float inv_n) {
    int c = threadIdx.x;
    float m = sum[c] * inv_n;
    float var = sumsq[c] * inv_n - m * m;
    float sc = gam[c] * rsqrtf(var + 1e-5f);
    scale[c] = sc;
    shift[c] = bet[c] - m * sc;
}

// ---------- BN1 + ReLU in-place on y ----------
__global__ __launch_bounds__(256) void bnpack_kernel(u32* __restrict__ y32,
                                                     const float* __restrict__ scale1,
                                                     const float* __restrict__ shift1) {
    const int b = blockIdx.x;
    const int t = threadIdx.x;
    const int c2 = (t & 127) * 2;
    const float s0 = scale1[c2],     s1 = scale1[c2 + 1];
    const float h0 = shift1[c2],     h1 = shift1[c2 + 1];
    u32* base = y32 + (size_t)b * 51200;
    for (int q = 0; q < 200; ++q) {
        const int idx = t + q * 256;
        u32 v = base[idx];
        float a = fmaxf(0.f, fmaf(s0, bflo(v), h0));
        float c = fmaxf(0.f, fmaf(s1, bfhi(v), h1));
        base[idx] = (u32)f2bf(a) | ((u32)f2bf(c) << 16);
    }
}

// ---------- conv2: implicit-im2col bf16 MFMA, kh-UNION staging ----------
// 512 blocks: g = blk>>1 (image pair), cb = (blk&1)*128 (co slice).
// 18 stages = 9 kh x 2 ci-halves. Per stage: stage the union of all 9 kw
// windows (2 img x 6 input rows x 20 cols x 128 ci = 61.4 KB) once, then
// compute 9 kw x 4 ccc x 12 = 432 MFMA/wave from it. y logical traffic drops
// 9x vs per-kk staging (1.5 GB -> 566 MB). All loads transient (load->LDS
// write inside the staging loop) -- no registers held across compute, no
// spill (r10's 875 MB scratch-write failure mode).
__global__ __launch_bounds__(256) void conv2_mfma_kernel(const u16* __restrict__ y,
                                                         const u16* __restrict__ w2r,
                                                         const float* __restrict__ b2,
                                                         float* __restrict__ z_raw,
                                                         float* __restrict__ sum2,
                                                         float* __restrict__ sumsq2) {
    __shared__ __align__(16) u16 stg[240 * 136];   // 65,280 B (< 64 KiB static limit)
    const int g  = blockIdx.x >> 1;
    const int cb = (blockIdx.x & 1) * 128;
    const int b0 = g * 2;
    const int t = threadIdx.x;
    const int wave = t >> 6, lane = t & 63;
    const int n16 = lane & 15, quad = lane >> 4;
    const int img = wave & 1, c64 = wave >> 1;     // wave: image, 64-co half of slice

    f32x4 zero = {0.f, 0.f, 0.f, 0.f};
    f32x4 acc[4][3];
#pragma unroll
    for (int ct = 0; ct < 4; ++ct)
#pragma unroll
        for (int pt = 0; pt < 3; ++pt) acc[ct][pt] = zero;

    // per-lane B-row bases (clamped: pos>=36 lanes read pos=35's valid data;
    // their acc is garbage but never stored -- epilogue guards pos<36)
    int brow[3];
#pragma unroll
    for (int pt = 0; pt < 3; ++pt) {
        int pos = pt * 16 + n16; if (pos > 35) pos = 35;
        const int oh = (pos * 43) >> 8;            // pos/6
        const int ow = pos - oh * 6;
        brow[pt] = (img * 6 + oh) * 20 + 2 * ow;   // + kw at use site
    }

    for (int kh = 0; kh < 9; ++kh) {
        for (int cp = 0; cp < 2; ++cp) {
            __syncthreads();
            // stage 240 rows (2 img x 6 oh-rows x 20 iw) x 256 B, 15 uint4/thread;
            // per (img,oh) the 20 iw rows are 10 KB contiguous in y -> coalesced
#pragma unroll
            for (int q = 0; q < 15; ++q) {
                const int v = t + q * 256;         // < 3840
                const int r = v >> 4, c16 = v & 15;
                const int i2 = (r >= 120) ? 1 : 0;
                const int rr = r - i2 * 120;
                const int oh = rr / 20;
                const int iw = rr - oh * 20;
                const int ip = (2 * oh + kh) * 20 + iw;
                const uint4 d = *((const uint4*)(y + ((size_t)(b0 + i2) * 400 + ip) * 256
                                                 + cp * 128 + c16 * 8));
                *((uint4*)(stg + r * 136 + c16 * 8)) = d;
            }
            __syncthreads();

#pragma unroll 3
            for (int kw = 0; kw < 9; ++kw) {
                const u16* wkk = w2r + (size_t)(kh * 9 + kw) * 65536 + (size_t)cp * 32768
                               + (cb + c64 * 64 + n16) * 32 + quad * 8;
#pragma unroll
                for (int ccc = 0; ccc < 4; ++ccc) {
                    bf16x8 bfr[3];
#pragma unroll
                    for (int pt = 0; pt < 3; ++pt)
                        bfr[pt] = *((const bf16x8*)(stg + (brow[pt] + kw) * 136
                                                    + ccc * 32 + quad * 8));
                    const u16* wa = wkk + (size_t)ccc * 8192;
#pragma unroll
                    for (int ct = 0; ct < 4; ++ct) {
                        bf16x8 afr = *((const bf16x8*)(wa + ct * 512));  // 16 co * 32
#pragma unroll
                        for (int pt = 0; pt < 3; ++pt)
                            acc[ct][pt] = __builtin_amdgcn_mfma_f32_16x16x32_bf16(
                                afr, bfr[pt], acc[ct][pt], 0, 0, 0);
                    }
                }
            }
        }
    }

    // epilogue: bias, store z[b0+img][co][36], BN2 stats (identical to r9)
#pragma unroll
    for (int ct = 0; ct < 4; ++ct) {
#pragma unroll
        for (int r = 0; r < 4; ++r) {
            const int co = cb + c64 * 64 + ct * 16 + quad * 4 + r;
            const float bias = b2[co];
            float s = 0.f, ss = 0.f;
#pragma unroll
            for (int pt = 0; pt < 3; ++pt) {
                const int pos = pt * 16 + n16;
                if (pos < 36) {
                    float v = acc[ct][pt][r] + bias;
                    z_raw[((size_t)(b0 + img) * 256 + co) * 36 + pos] = v;
                    s += v; ss += v * v;
                }
            }
#pragma unroll
            for (int m = 1; m < 16; m <<= 1) {
                s  += __shfl_xor(s,  m, 64);
                ss += __shfl_xor(ss, m, 64);
            }
            if (n16 == 0) { atomicAdd(&sum2[co], s); atomicAdd(&sumsq2[co], ss); }
        }
    }
}

// ---------- BN2 + ReLU + capsule transpose: ut fp16 [b][d][i] ----------
__global__ __launch_bounds__(256) void ubuild_kernel(const float* __restrict__ z_raw,
                                                     const float* __restrict__ scale2,
                                                     const float* __restrict__ shift2,
                                                     u16* __restrict__ ut16) {
    const int b = blockIdx.x;
    const int t = threadIdx.x;            // c
    const int d = t >> 5, m = t & 31;
    const float sc = scale2[t], sh = shift2[t];
    const float* zp = z_raw + ((size_t)b * 256 + t) * 36;
    u32* up = (u32*)(ut16 + ((size_t)b * 8 + d) * 1152 + m * 36);
#pragma unroll
    for (int q = 0; q < 18; ++q) {
        float v0 = fmaxf(0.f, fmaf(sc, zp[2 * q],     sh));
        float v1 = fmaxf(0.f, fmaf(sc, zp[2 * q + 1], sh));
        up[q] = (u32)f2h(v0) | ((u32)f2h(v1) << 16);
    }
}

// ---------- u_hat_f16[b][i][je] = sum_d ut[b][d][i]*Wt2[i][je][d]; + s0 partials ----------
__global__ __launch_bounds__(256) void uhat_kernel(const u16* __restrict__ ut16,
                                                   const float* __restrict__ Wt2,
                                                   u16* __restrict__ u_hat,
                                                   float* __restrict__ s0g) {
    __shared__ float utl[8 * 8 * 144];    // [bb][d][ii], 36 KB
    const int bg = blockIdx.x >> 3;       // 64 image-groups of 8
    const int ic = blockIdx.x & 7;        // 8 i-chunks of 144
    const int b0 = bg * 8, i0 = ic * 144;
    for (int v = threadIdx.x; v < 8 * 8 * 144; v += 256) {
        int ii = v % 144; int d = (v / 144) & 7; int bb = v / 1152;
        utl[v] = h2f(ut16[(size_t)(b0 + bb) * 9216 + d * 1152 + i0 + ii]);
    }
    __syncthreads();
    for (int q = 0; q < 90; ++q) {
        int o = q * 256 + threadIdx.x;    // 144*160 = 23040 = 90*256
        int ii = o / 160, je = o - ii * 160;
        const float* wp = Wt2 + ((size_t)(i0 + ii) * 160 + je) * 8;
        float w[8];
#pragma unroll
        for (int d = 0; d < 8; ++d) w[d] = wp[d];
#pragma unroll
        for (int bb = 0; bb < 8; ++bb) {
            float acc = 0.f;
#pragma unroll
            for (int d = 0; d < 8; ++d) acc = fmaf(w[d], utl[bb * 1152 + d * 144 + ii], acc);
            u_hat[(size_t)(b0 + bb) * 184320 + (size_t)(i0 + ii) * 160 + je] = f2h(acc);
        }
    }
    __syncthreads();   // drains stores (compiler emits vmcnt(0) before barrier)
    // s0 partials: 1280 (bb,je) pairs, 5 per thread; re-read own L2-hot tile
#pragma unroll
    for (int p = 0; p < 5; ++p) {
        const int pair = p * 256 + threadIdx.x;
        const int bb = pair / 160, je = pair - (pair / 160) * 160;
        const u16* up = u_hat + (size_t)(b0 + bb) * 184320 + (size_t)i0 * 160 + je;
        float s = 0.f;
        for (int ii = 0; ii < 144; ++ii) s += h2f(up[(size_t)ii * 160]);
        atomicAdd(&s0g[(size_t)(b0 + bb) * 160 + je], s);
    }
}

// ---------- fused routing, iterations 1..4 (iter-0 s precomputed), double-buffered ----------
__global__ __launch_bounds__(384) void routing_kernel(const u16* __restrict__ u_hat,
                                                      const float* __restrict__ s0g,
                                                      float* __restrict__ out) {
    __shared__ __align__(16) u16 uhs[2][96 * 168]; // 2 x 31.5 KB, row pad 168
    __shared__ float cl[10 * 96];
    __shared__ float part[320];
    __shared__ float sv[160];
    const int t = threadIdx.x;
    const int b = blockIdx.x;
    const u16* uh = u_hat + (size_t)b * 184320;
    const int hB = (t < 320) ? (t / 160) : 0;
    const int je = (t < 320) ? (t - hB * 160) : 0;
    const int jB = je >> 4;

    float bl[12][10];
#pragma unroll
    for (int c = 0; c < 12; ++c)
#pragma unroll
        for (int j = 0; j < 10; ++j) bl[c][j] = 0.f;

    // issue chunk-0 loads, then v0 = squash(0.1 * s0)
    uint4 rg[5];
    {
        const u16* src = uh;
#pragma unroll
        for (int q = 0; q < 5; ++q) {
            int v = t + q * 384, r = v / 20, c16 = v - r * 20;
            rg[q] = *((const uint4*)(src + r * 160 + c16 * 8));
        }
    }
    if (t < 160) sv[t] = 0.1f * s0g[(size_t)b * 160 + t];
    __syncthreads();
    if (t < 10) {
        float n2 = 0.f;
#pragma unroll
        for (int e2 = 0; e2 < 16; ++e2) { float xx = sv[t * 16 + e2]; n2 += xx * xx; }
        float n = sqrtf(n2);
        float f = n / (n2 + 1.f);
#pragma unroll
        for (int e2 = 0; e2 < 16; ++e2) sv[t * 16 + e2] *= f;
    }
    // write chunk 0 into buf 0
#pragma unroll
    for (int q = 0; q < 5; ++q) {
        int v = t + q * 384, r = v / 20, c16 = v - r * 20;
        *((uint4*)(&uhs[0][r * 168 + c16 * 8])) = rg[q];
    }

    for (int k = 1; k <= 4; ++k) {
        float sacc = 0.f;
        for (int c = 0; c < 12; ++c) {
            const int p = c & 1;
            const bool last = (k == 4) && (c == 11);
            __syncthreads();               // buf[p] writes + sv/cl updates visible
            if (!last) {                   // issue next-chunk loads (wraps to 0 across k)
                const int nc = (c == 11) ? 0 : c + 1;
                const u16* src = uh + (size_t)nc * 15360;
#pragma unroll
                for (int q = 0; q < 5; ++q) {
                    int v = t + q * 384, r = v / 20, c16 = v - r * 20;
                    rg[q] = *((const uint4*)(src + r * 160 + c16 * 8));
                }
            }
            if (t < 96) {                  // phase A
                const u16* row = uhs[p] + t * 168;
                float bj[10];
#pragma unroll
                for (int j = 0; j < 10; ++j) {
                    uint4 a = *((const uint4*)(row + j * 16));
                    uint4 bq = *((const uint4*)(row + j * 16 + 8));
                    const float* vv = &sv[j * 16];
                    float dj = h2f((u16)(a.x & 0xffff)) * vv[0]  + h2f((u16)(a.x >> 16)) * vv[1]
                             + h2f((u16)(a.y & 0xffff)) * vv[2]  + h2f((u16)(a.y >> 16)) * vv[3]
                             + h2f((u16)(a.z & 0xffff)) * vv[4]  + h2f((u16)(a.z >> 16)) * vv[5]
                             + h2f((u16)(a.w & 0xffff)) * vv[6]  + h2f((u16)(a.w >> 16)) * vv[7]
                             + h2f((u16)(bq.x & 0xffff)) * vv[8]  + h2f((u16)(bq.x >> 16)) * vv[9]
                             + h2f((u16)(bq.y & 0xffff)) * vv[10] + h2f((u16)(bq.y >> 16)) * vv[11]
                             + h2f((u16)(bq.z & 0xffff)) * vv[12] + h2f((u16)(bq.z >> 16)) * vv[13]
                             + h2f((u16)(bq.w & 0xffff)) * vv[14] + h2f((u16)(bq.w >> 16)) * vv[15];
                    bl[c][j] += dj;
                    bj[j] = bl[c][j];
                }
                float mx = bj[0];
#pragma unroll
                for (int j = 1; j < 10; ++j) mx = fmaxf(mx, bj[j]);
                float s = 0.f;
#pragma unroll
                for (int j = 0; j < 10; ++j) { bj[j] = __expf(bj[j] - mx); s += bj[j]; }
                float inv = 1.f / s;
#pragma unroll
                for (int j = 0; j < 10; ++j) cl[j * 96 + t] = bj[j] * inv;
            }
            __syncthreads();               // cl visible
            if (t < 320) {                 // phase B
                const int r0 = hB * 48;
#pragma unroll 4
                for (int il = 0; il < 48; ++il) {
                    const int r = r0 + il;
                    sacc = fmaf(cl[jB * 96 + r], h2f(uhs[p][r * 168 + je]), sacc);
                }
            }
            if (!last) {                   // write next chunk into the other buffer
#pragma unroll
                for (int q = 0; q < 5; ++q) {
                    int v = t + q * 384, r = v / 20, c16 = v - r * 20;
                    *((uint4*)(&uhs[p ^ 1][r * 168 + c16 * 8])) = rg[q];
                }
            }
        }
        __syncthreads();
        if (t < 320) part[t] = sacc;
        __syncthreads();
        if (t < 160) sv[t] = part[t] + part[t + 160];
        __syncthreads();
        if (t < 10) {
            float n2 = 0.f;
#pragma unroll
            for (int e2 = 0; e2 < 16; ++e2) { float xx = sv[t * 16 + e2]; n2 += xx * xx; }
            float n = sqrtf(n2);
            float f = n / (n2 + 1.f);
#pragma unroll
            for (int e2 = 0; e2 < 16; ++e2) sv[t * 16 + e2] *= f;
        }
    }
    __syncthreads();
    if (t < 160) out[(size_t)b * 160 + t] = sv[t];
}

extern "C" void kernel_launch(void* const* d_in, const int* in_sizes, int n_in,
                              void* d_out, int out_size, void* d_ws, size_t ws_size,
                              hipStream_t stream) {
    const float* x   = (const float*)d_in[0];
    const float* w1  = (const float*)d_in[1];
    const float* b1  = (const float*)d_in[2];
    const float* g1  = (const float*)d_in[3];
    const float* be1 = (const float*)d_in[4];
    const float* w2  = (const float*)d_in[5];
    const float* b2  = (const float*)d_in[6];
    const float* g2  = (const float*)d_in[7];
    const float* be2 = (const float*)d_in[8];
    const float* W   = (const float*)d_in[9];
    float* out = (float*)d_out;

    // ---- workspace layout (peak 213,524,480 B == proven-safe bound) ----
    const size_t OFF_UHAT = 8192;                       // 188,743,680 B (fp16, full batch)
    const size_t OFF_Y    = 8192;                       // 104,857,600 B (in u_hat region)
    const size_t OFF_W2R  = 104865792ull;               //  10,616,832 B (in u_hat region)
    const size_t OFF_Z    = 126099456ull;               //  18,874,368 B (in u_hat region)
    const size_t OFF_UT   = 188751872ull;               //   9,437,184 B (ut fp16)
    const size_t OFF_S0   = 198189056ull;               //     327,680 B (s0)
    const size_t OFF_WT   = 207626240ull;               //   5,898,240 B
    const size_t WS_NEED  = 213524480ull;
    if (ws_size < WS_NEED) return;

    char* ws = (char*)d_ws;
    float* sum1   = (float*)(ws + 0);
    float* sumsq1 = (float*)(ws + 1024);
    float* sum2   = (float*)(ws + 2048);
    float* sumsq2 = (float*)(ws + 3072);
    float* scale1 = (float*)(ws + 4096);
    float* shift1 = (float*)(ws + 5120);
    float* scale2 = (float*)(ws + 6144);
    float* shift2 = (float*)(ws + 7168);
    u16*   y     = (u16*)(ws + OFF_Y);
    u16*   w2r   = (u16*)(ws + OFF_W2R);
    float* z_raw = (float*)(ws + OFF_Z);
    u16*   ut16  = (u16*)(ws + OFF_UT);
    float* s0g   = (float*)(ws + OFF_S0);
    float* Wt2   = (float*)(ws + OFF_WT);
    u16*   u_hat = (u16*)(ws + OFF_UHAT);

    hipMemsetAsync(ws, 0, 4096, stream);               // BN sums
    hipMemsetAsync(ws + OFF_S0, 0, 327680, stream);    // s0 accumulators

    hipLaunchKernelGGL(repack_w2_kernel, dim3(20736), dim3(256), 0, stream, w2, w2r);
    hipLaunchKernelGGL(repack_W_kernel,  dim3(5760),  dim3(256), 0, stream, W, Wt2);
    hipLaunchKernelGGL(conv1_kernel,     dim3(512),   dim3(256), 0, stream,
                       x, w1, b1, y, sum1, sumsq1);
    hipLaunchKernelGGL(finalize_bn_kernel, dim3(1), dim3(256), 0, stream,
                       sum1, sumsq1, g1, be1, scale1, shift1, 1.f / 204800.f);
    hipLaunchKernelGGL(bnpack_kernel,    dim3(512),   dim3(256), 0, stream,
                       (u32*)y, scale1, shift1);
    hipLaunchKernelGGL(conv2_mfma_kernel, dim3(512),  dim3(256), 0, stream,
                       y, w2r, b2, z_raw, sum2, sumsq2);
    hipLaunchKernelGGL(finalize_bn_kernel, dim3(1), dim3(256), 0, stream,
                       sum2, sumsq2, g2, be2, scale2, shift2, 1.f / 18432.f);
    hipLaunchKernelGGL(ubuild_kernel,    dim3(512),   dim3(256), 0, stream,
                       z_raw, scale2, shift2, ut16);
    hipLaunchKernelGGL(uhat_kernel,      dim3(512),   dim3(256), 0, stream,
                       ut16, Wt2, u_hat, s0g);
    hipLaunchKernelGGL(routing_kernel,   dim3(512),   dim3(384), 0, stream,
                       u_hat, s0g, out);
}